// Round 6
// baseline (174.467 us; speedup 1.0000x reference)
//
#include <hip/hip_runtime.h>
#include <hip/hip_bf16.h>

// Problem constants (SparseMoE: D=512, H=2048, O=512, E=8, K=2, CF=1.0)
#define NTOK 16384
#define DDIM 512
#define HDIM 2048
#define ODIM 512
#define NE 8
#define CAP 2048   // max(int(N/E*CF), 4) = 2048

typedef __attribute__((ext_vector_type(8))) short short8v;
typedef __attribute__((ext_vector_type(4))) short short4v;
typedef __attribute__((ext_vector_type(8))) unsigned short ushort8v;
typedef __attribute__((ext_vector_type(4))) float f32x4;

static __device__ __forceinline__ unsigned short f2bf(float f) {
  __hip_bfloat16 h = __float2bfloat16(f);
  return __builtin_bit_cast(unsigned short, h);
}

// async global->LDS, 16B per lane; LDS dest = wave-uniform base + lane*16
#define GLOAD_LDS16(gp, lp)                                               \
  __builtin_amdgcn_global_load_lds(                                       \
      (const __attribute__((address_space(1))) void*)(gp),                \
      (__attribute__((address_space(3))) void*)(lp), 16, 0, 0)

// ---------------- fused prep: transpose w1, transpose w2, gating
// blocks [0,8192): w1 (E,512,2048)->(E,2048,512) bf16
// blocks [8192,16384): w2 (E,2048,512)->(E,512,2048) bf16
// blocks [16384,20480): gate (4 tokens per block)
__device__ __forceinline__ void transpose_block(const float* __restrict__ src,
                                                __hip_bfloat16* __restrict__ dst,
                                                int R, int C, int b) {
  __shared__ float tile[32][33];
  int nx = C >> 5, ny = R >> 5;
  int x = b % nx, y = (b / nx) % ny, e = b / (nx * ny);
  size_t base = (size_t)e * R * C;
  int c0 = x * 32, r0 = y * 32;
  int tx = threadIdx.x & 31, ty = threadIdx.x >> 5;
#pragma unroll
  for (int i = 0; i < 32; i += 8)
    tile[ty + i][tx] = src[base + (size_t)(r0 + ty + i) * C + c0 + tx];
  __syncthreads();
#pragma unroll
  for (int i = 0; i < 32; i += 8)
    dst[base + (size_t)(c0 + ty + i) * R + r0 + tx] = __float2bfloat16(tile[tx][ty + i]);
}

__global__ void k_prep(const float* __restrict__ x, const float* __restrict__ gw,
                       const float* __restrict__ gb, const float* __restrict__ w1,
                       __hip_bfloat16* __restrict__ w1t, const float* __restrict__ w2,
                       __hip_bfloat16* __restrict__ w2t, float* __restrict__ gate_probs,
                       int2* __restrict__ tk_e, float2* __restrict__ tk_w,
                       int* __restrict__ token_slot) {
  int b = blockIdx.x;
  if (b < 8192) { transpose_block(w1, w1t, DDIM, HDIM, b); return; }
  if (b < 16384) { transpose_block(w2, w2t, HDIM, ODIM, b - 8192); return; }
  b -= 16384;
  __shared__ float gws[DDIM * 9];  // pad 8->9 floats per row: bank-conflict-free
  int tid = threadIdx.x;
  for (int i = tid; i < DDIM * NE; i += 256) {
    int d = i >> 3, e = i & 7;
    gws[d * 9 + e] = gw[i];
  }
  __syncthreads();
  int wid = tid >> 6, lane = tid & 63;
  int t = b * 4 + wid;
  const float* xr = x + (size_t)t * DDIM;
  float acc[NE] = {0.f, 0.f, 0.f, 0.f, 0.f, 0.f, 0.f, 0.f};
#pragma unroll
  for (int j = 0; j < 8; ++j) {
    float xv = xr[lane + 64 * j];
    const float* g = &gws[(lane + 64 * j) * 9];
#pragma unroll
    for (int e = 0; e < NE; ++e) acc[e] += xv * g[e];
  }
#pragma unroll
  for (int e = 0; e < NE; ++e) {
#pragma unroll
    for (int off = 32; off > 0; off >>= 1) acc[e] += __shfl_xor(acc[e], off, 64);
  }
  if (lane == 0) {
    float p[NE];
    float m = -1e30f;
#pragma unroll
    for (int e = 0; e < NE; ++e) { p[e] = acc[e] + gb[e]; m = fmaxf(m, p[e]); }
    float s = 0.f;
#pragma unroll
    for (int e = 0; e < NE; ++e) { p[e] = expf(p[e] - m); s += p[e]; }
    float inv = 1.f / s;
#pragma unroll
    for (int e = 0; e < NE; ++e) { p[e] *= inv; gate_probs[(size_t)t * NE + e] = p[e]; }
    int i1 = 0; float p1 = p[0];
#pragma unroll
    for (int e = 1; e < NE; ++e) if (p[e] > p1) { p1 = p[e]; i1 = e; }
    int i2 = -1; float p2 = -1e30f;
#pragma unroll
    for (int e = 0; e < NE; ++e) if (e != i1 && p[e] > p2) { p2 = p[e]; i2 = e; }
    float wsum = p1 + p2;
    tk_e[t] = make_int2(i1, i2);
    tk_w[t] = make_float2(p1 / wsum, p2 / wsum);
    token_slot[2 * t] = -1;
    token_slot[2 * t + 1] = -1;
  }
}

// ---------------- dispatch: per-expert FCFS capacity assignment (block scan)
__global__ void k_dispatch(const int2* __restrict__ tk_e, int* __restrict__ token_slot,
                           int* __restrict__ expert_tokens) {
  int e = blockIdx.x;
  int tid = threadIdx.x;
  int lane = tid & 63, w = tid >> 6;   // 16 waves
  __shared__ int wave_cnt[16];
  int base = 0;
  for (int chunk = 0; chunk < NTOK / 1024; ++chunk) {
    int t = chunk * 1024 + tid;
    int2 te = tk_e[t];
    int k = (te.x == e) ? 0 : ((te.y == e) ? 1 : -1);
    bool flag = (k >= 0);
    unsigned long long m = __ballot(flag);
    int pre = __popcll(m & ((1ull << lane) - 1ull));
    __syncthreads();
    if (lane == 0) wave_cnt[w] = __popcll(m);
    __syncthreads();
    int off = 0, total = 0;
#pragma unroll
    for (int i = 0; i < 16; ++i) {
      off += (i < w) ? wave_cnt[i] : 0;
      total += wave_cnt[i];
    }
    int rank = base + off + pre;
    if (flag && rank < CAP) {
      expert_tokens[e * CAP + rank] = t;
      token_slot[2 * t + k] = e * CAP + rank;
    }
    base += total;
  }
  int nvalid = base < CAP ? base : CAP;
  for (int s = nvalid + tid; s < CAP; s += 1024)
    expert_tokens[e * CAP + s] = 0;  // padded slots: weight 0, never combined
}

// ---------------- gather: xg[e][c][:] = bf16(x[expert_tokens[e*CAP+c]][:])
__global__ void k_gather(const float* __restrict__ x,
                         const int* __restrict__ expert_tokens,
                         __hip_bfloat16* __restrict__ xg) {
  int tid = threadIdx.x, wid = tid >> 6, lane = tid & 63;
  int slot = blockIdx.x * 4 + wid;  // 0..E*CAP-1
  int tok = expert_tokens[slot];
  const float4* src = reinterpret_cast<const float4*>(x + (size_t)tok * DDIM) + lane * 2;
  float4 u = src[0], v = src[1];
  ushort8v o;
  o[0] = f2bf(u.x); o[1] = f2bf(u.y); o[2] = f2bf(u.z); o[3] = f2bf(u.w);
  o[4] = f2bf(v.x); o[5] = f2bf(v.y); o[6] = f2bf(v.z); o[7] = f2bf(v.w);
  *reinterpret_cast<ushort8v*>(xg + (size_t)slot * DDIM + lane * 8) = o;
}

// sigmoid-form tanh-GELU: |err vs exact erf-gelu| < ~1e-3, safe for bf16 out
static __device__ __forceinline__ float gelu_fast(float v) {
  float z = 1.5957691216057308f * (v + 0.044715f * v * v * v);
  return v / (1.f + __expf(-z));
}

// ---------------- pipelined GEMM: BM=256 x BN=128 tile, BK=32, 4 waves,
// wave-tile 128x64 (8 M-frags x 4 N-frags = 32 MFMA, 12 ds_read per K-step).
// 2 LDS buffers (48 KB), counted vmcnt: tile t+1 stays in flight (6 loads).
// Per K-step: vmcnt(6)->barrier-> read A-half0+B -> lgkm -> read A-half1
//   || MFMA(half0) -> lgkm -> barrier -> stage(t+2 into this buf) || MFMA(half1).
// A = weights (E, M, K): fragment rows -> output features (vector stores)
// B = tokens  (E, CAP, K); C = (E, CAP, M) token-major.
// Swizzle per rule #21: linear gload_lds dest + inverse-swizzled global
// source + swizzled ds_read (16B slot s of row rr holds k16 = s ^ ((rr>>1)&3)).
template <int K, int M, bool GELU, typename OutT>
__global__ __launch_bounds__(256, 2) void k_gemm(
    const __hip_bfloat16* __restrict__ A, const __hip_bfloat16* __restrict__ B,
    const float* __restrict__ bias, OutT* __restrict__ C) {
  __shared__ char lds[2][24576];  // [buf][ A:16KB (256 rows x 64B) | B:8KB ]
  // XCD-aware bijective remap (grid size is a multiple of 8)
  int gx = gridDim.x, gy = gridDim.y;
  int lin = (blockIdx.z * gy + blockIdx.y) * gx + blockIdx.x;
  int total = gx * gy * (int)gridDim.z;
  int cpx = total >> 3;
  lin = (lin & 7) * cpx + (lin >> 3);
  int gxy = gx * gy;
  int e = lin / gxy;
  int rem = lin - e * gxy;
  int mt = rem / gx, nt = rem - mt * gx;

  const int m0 = mt * 256, n0 = nt * 128;
  const int tid = threadIdx.x;
  const int lane = tid & 63, wid = tid >> 6;
  const int wr = wid >> 1, wc = wid & 1;   // wave-tile: M-half (128), N-half (64)
  const int lrow = lane & 15, kseg = lane >> 4;

  const int r0 = tid >> 2;                     // staging row 0..63
  const int sc = (tid & 3) ^ ((r0 >> 1) & 3);  // inverse-swizzled source k16
  const int cb = (tid & 192) * 16;             // wave-uniform LDS byte base
  const __hip_bfloat16* Ab = A + ((size_t)e * M + m0) * K;
  const __hip_bfloat16* Bb = B + ((size_t)e * CAP + n0) * K;

  // 6 gloads/thread/tile: A rows r0+64j (j=0..3), B rows r0+64j (j=0..1)
#define STAGE(buf, kk)                                                           \
  do {                                                                           \
    _Pragma("unroll")                                                            \
    for (int j = 0; j < 4; ++j)                                                  \
      GLOAD_LDS16(Ab + (size_t)(r0 + 64 * j) * K + (kk) + sc * 8,                \
                  lds[buf] + j * 4096 + cb);                                     \
    _Pragma("unroll")                                                            \
    for (int j = 0; j < 2; ++j)                                                  \
      GLOAD_LDS16(Bb + (size_t)(r0 + 64 * j) * K + (kk) + sc * 8,                \
                  lds[buf] + 16384 + j * 4096 + cb);                             \
  } while (0)

#define READ_A(dst, bi, half)                                                    \
  do {                                                                           \
    _Pragma("unroll")                                                            \
    for (int mm = 0; mm < 4; ++mm) {                                             \
      int rr = wr * 128 + (half) * 64 + mm * 16 + lrow;                          \
      int ks = kseg ^ ((rr >> 1) & 3);                                           \
      dst[mm] = *reinterpret_cast<const short8v*>(lds[bi] + rr * 64 + ks * 16);  \
    }                                                                            \
  } while (0)

#define READ_B(dst, bi)                                                          \
  do {                                                                           \
    _Pragma("unroll")                                                            \
    for (int nn = 0; nn < 4; ++nn) {                                             \
      int rr = wc * 64 + nn * 16 + lrow;                                         \
      int ks = kseg ^ ((rr >> 1) & 3);                                           \
      dst[nn] = *reinterpret_cast<const short8v*>(lds[bi] + 16384 + rr * 64 +    \
                                                  ks * 16);                      \
    }                                                                            \
  } while (0)

#define MFMA_HALF(afr, half)                                                     \
  do {                                                                           \
    __builtin_amdgcn_s_setprio(1);                                               \
    _Pragma("unroll")                                                            \
    for (int mm = 0; mm < 4; ++mm)                                               \
      _Pragma("unroll")                                                          \
      for (int nn = 0; nn < 4; ++nn)                                             \
        acc[(half) * 4 + mm][nn] = __builtin_amdgcn_mfma_f32_16x16x32_bf16(      \
            afr[mm], bfr[nn], acc[(half) * 4 + mm][nn], 0, 0, 0);                \
    __builtin_amdgcn_s_setprio(0);                                               \
  } while (0)

  f32x4 acc[8][4] = {};
  short8v a0[4], a1[4], bfr[4];
  const int T = K >> 5;  // 16 (GEMM1) or 64 (GEMM2)

  STAGE(0, 0);
  STAGE(1, 32);
  int bt = 0;
  for (int t = 0; t < T; ++t) {
    if (t < T - 1) asm volatile("s_waitcnt vmcnt(6)" ::: "memory");
    else           asm volatile("s_waitcnt vmcnt(0)" ::: "memory");
    __builtin_amdgcn_s_barrier();        // tile t resident & visible
    READ_A(a0, bt, 0);
    READ_B(bfr, bt);
    asm volatile("s_waitcnt lgkmcnt(0)" ::: "memory");
    __builtin_amdgcn_sched_barrier(0);   // rule #18 fence
    READ_A(a1, bt, 1);                   // overlaps MFMA of half0
    MFMA_HALF(a0, 0);
    asm volatile("s_waitcnt lgkmcnt(0)" ::: "memory");
    __builtin_amdgcn_sched_barrier(0);
    __builtin_amdgcn_s_barrier();        // all waves done reading buf bt
    if (t + 2 < T) STAGE(bt, (t + 2) * 32);  // overlaps MFMA of half1
    MFMA_HALF(a1, 1);
    bt ^= 1;
  }
#undef STAGE
#undef READ_A
#undef READ_B
#undef MFMA_HALF

  // epilogue: lane holds 4 consecutive output-features (rows of A) at one token
#pragma unroll
  for (int half = 0; half < 2; ++half) {
#pragma unroll
    for (int mm = 0; mm < 4; ++mm) {
      int mrow = m0 + wr * 128 + half * 64 + mm * 16 + kseg * 4;
      float4 bv = *reinterpret_cast<const float4*>(&bias[e * M + mrow]);
#pragma unroll
      for (int nn = 0; nn < 4; ++nn) {
        int token = n0 + wc * 64 + nn * 16 + lrow;
        float v0 = acc[half * 4 + mm][nn][0] + bv.x;
        float v1 = acc[half * 4 + mm][nn][1] + bv.y;
        float v2 = acc[half * 4 + mm][nn][2] + bv.z;
        float v3 = acc[half * 4 + mm][nn][3] + bv.w;
        if (GELU) {
          v0 = gelu_fast(v0); v1 = gelu_fast(v1);
          v2 = gelu_fast(v2); v3 = gelu_fast(v3);
        }
        OutT* cp = C + ((size_t)e * CAP + token) * M + mrow;
        if constexpr (__is_same(OutT, __hip_bfloat16)) {
          short4v o;
          o[0] = (short)f2bf(v0); o[1] = (short)f2bf(v1);
          o[2] = (short)f2bf(v2); o[3] = (short)f2bf(v3);
          *reinterpret_cast<short4v*>(cp) = o;  // 8B store
        } else {
          float4 o = {v0, v1, v2, v3};
          *reinterpret_cast<float4*>(cp) = o;   // 16B store
        }
      }
    }
  }
}

// ---------------- combine: per token, sum its <=2 weighted expert rows
__global__ void k_combine(const float* __restrict__ outbuf,
                          const int* __restrict__ token_slot,
                          const float2* __restrict__ tk_w,
                          float* __restrict__ comb) {
  int tid = threadIdx.x;
  int wid = tid >> 6, lane = tid & 63;
  int t = blockIdx.x * 4 + wid;
  int s0 = token_slot[2 * t], s1 = token_slot[2 * t + 1];
  float2 w = tk_w[t];
  float r[8] = {0.f, 0.f, 0.f, 0.f, 0.f, 0.f, 0.f, 0.f};
  if (s0 >= 0) {
    const float4* p = reinterpret_cast<const float4*>(outbuf + (size_t)s0 * ODIM + lane * 8);
    float4 a = p[0], b = p[1];
    r[0] += w.x * a.x; r[1] += w.x * a.y; r[2] += w.x * a.z; r[3] += w.x * a.w;
    r[4] += w.x * b.x; r[5] += w.x * b.y; r[6] += w.x * b.z; r[7] += w.x * b.w;
  }
  if (s1 >= 0) {
    const float4* p = reinterpret_cast<const float4*>(outbuf + (size_t)s1 * ODIM + lane * 8);
    float4 a = p[0], b = p[1];
    r[0] += w.y * a.x; r[1] += w.y * a.y; r[2] += w.y * a.z; r[3] += w.y * a.w;
    r[4] += w.y * b.x; r[5] += w.y * b.y; r[6] += w.y * b.z; r[7] += w.y * b.w;
  }
  float4* q = reinterpret_cast<float4*>(comb + (size_t)t * ODIM + lane * 8);
  float4 o0 = {r[0], r[1], r[2], r[3]};
  float4 o1 = {r[4], r[5], r[6], r[7]};
  q[0] = o0;
  q[1] = o1;
}

extern "C" void kernel_launch(void* const* d_in, const int* in_sizes, int n_in,
                              void* d_out, int out_size, void* d_ws, size_t ws_size,
                              hipStream_t stream) {
  const float* x      = (const float*)d_in[0];
  const float* gate_w = (const float*)d_in[1];
  const float* gate_b = (const float*)d_in[2];
  const float* w1     = (const float*)d_in[3];
  const float* b1     = (const float*)d_in[4];
  const float* w2     = (const float*)d_in[5];
  const float* b2     = (const float*)d_in[6];

  float* comb = (float*)d_out;                     // (8,2048,512) f32
  float* gate_probs = comb + (size_t)NTOK * ODIM;  // (16384,8) f32

  // workspace layout (~128.5 MiB; xg aliases outbuf - disjoint lifetimes)
  char* ws = (char*)d_ws;
  __hip_bfloat16* w1t    = (__hip_bfloat16*)(ws);              // [0,16M)   (E,H,D)
  __hip_bfloat16* w2t    = (__hip_bfloat16*)(ws + 16777216);   // [16,32M)  (E,O,H)
  __hip_bfloat16* hbuf   = (__hip_bfloat16*)(ws + 33554432);   // [32,96M)  (E,CAP,H)
  __hip_bfloat16* xg     = (__hip_bfloat16*)(ws + 100663296);  // [96,112M) (E,CAP,D)
  float*          outbuf = (float*)(ws + 100663296);           // [96,128M) (E,CAP,O)
  int*   expert_tokens   = (int*)(ws + 134217728);
  int2*  tk_e            = (int2*)(ws + 134283264);
  float2* tk_w           = (float2*)(ws + 134414336);
  int*   token_slot      = (int*)(ws + 134545408);

  // prep: blocks [0,8192) w1-transpose, [8192,16384) w2-transpose, rest gate
  k_prep<<<16384 + NTOK / 4, 256, 0, stream>>>(x, gate_w, gate_b, w1, w1t, w2, w2t,
                                               gate_probs, tk_e, tk_w, token_slot);
  k_dispatch<<<NE, 1024, 0, stream>>>(tk_e, token_slot, expert_tokens);
  k_gather<<<NE * CAP / 4, 256, 0, stream>>>(x, expert_tokens, xg);
  // GEMM1: A=w1t (E,H,D) M=HDIM, B=xg, C=hbuf (E,CAP,H) bf16 + GELU
  k_gemm<DDIM, HDIM, true, __hip_bfloat16>
      <<<dim3(CAP / 128, HDIM / 256, NE), 256, 0, stream>>>(w1t, xg, b1, hbuf);
  // GEMM2: A=w2t (E,O,H) M=ODIM, B=hbuf, C=outbuf (E,CAP,O) f32
  k_gemm<HDIM, ODIM, false, float>
      <<<dim3(CAP / 128, ODIM / 256, NE), 256, 0, stream>>>(w2t, hbuf, b2, outbuf);
  k_combine<<<NTOK / 4, 256, 0, stream>>>(outbuf, token_slot, tk_w, comb);
}